// Round 20
// baseline (4107.663 us; speedup 1.0000x reference)
//
#include <hip/hip_runtime.h>
#include <math.h>

#define NC 64
#define NH 256
#define NW 256
#define NM 32
#define NKY 64
#define HW 65536

typedef short bfrag __attribute__((ext_vector_type(8)));   // 8 bf16 (4 VGPR)
typedef float facc  __attribute__((ext_vector_type(4)));   // 4 f32 acc
#define MFMA(a,b,c) __builtin_amdgcn_mfma_f32_16x16x32_bf16(a,b,c,0,0,0)

static constexpr float PI_F = 3.14159265358979323846f;

__device__ __forceinline__ unsigned short f2b(float f) {  // f32 -> bf16 RNE
  unsigned b = __float_as_uint(f);
  return (unsigned short)((b + 0x7FFFu + ((b >> 16) & 1u)) >> 16);
}
__device__ __forceinline__ float b2f(unsigned short h) {
  return __uint_as_float((unsigned)h << 16);
}
// pack hi/lo split of f32 into one uint: (lo<<16)|hi
__device__ __forceinline__ unsigned packsplit(float v) {
  unsigned short hi = f2b(v);
  unsigned short lo = f2b(v - b2f(hi));
  return (unsigned)hi | ((unsigned)lo << 16);
}
// LDS tile addressing: [ch][64 px], XOR-swizzled to spread quarter-wave rows
__device__ __forceinline__ int swz(int ch, int px) {
  return ch * 64 + (px ^ (((ch >> 3) & 3) << 4));
}
// build hi/lo bfrags from 8 packed uints via v_perm (2 ops per uint pair)
#define UNPACK8(U, BH, BL)                                              \
  {                                                                     \
    BH.q.x = __builtin_amdgcn_perm(U[1], U[0], 0x05040100u);            \
    BH.q.y = __builtin_amdgcn_perm(U[3], U[2], 0x05040100u);            \
    BH.q.z = __builtin_amdgcn_perm(U[5], U[4], 0x05040100u);            \
    BH.q.w = __builtin_amdgcn_perm(U[7], U[6], 0x05040100u);            \
    BL.q.x = __builtin_amdgcn_perm(U[1], U[0], 0x07060302u);            \
    BL.q.y = __builtin_amdgcn_perm(U[3], U[2], 0x07060302u);            \
    BL.q.z = __builtin_amdgcn_perm(U[5], U[4], 0x07060302u);            \
    BL.q.w = __builtin_amdgcn_perm(U[7], U[6], 0x07060302u);            \
  }
typedef union { bfrag f; uint4 q; } fragu;

// branchless erf-based exact GELU (A&S 7.1.26, |err| < 1.5e-7)
__device__ __forceinline__ float gelu_f(float x) {
  float z = fabsf(x) * 0.70710678118654752f;
  float t = 1.0f / (1.0f + 0.3275911f * z);
  float e = __expf(-z * z);
  float p = t * (0.254829592f + t * (-0.284496736f + t * (1.421413741f +
            t * (-1.453152027f + t * 1.061405429f))));
  float er = copysignf(1.0f - p * e, x);
  return 0.5f * x * (1.0f + er);
}

// ================= table builders (split-bf16 DFT matrices) =================
__global__ void k_tEy(unsigned short* __restrict__ eh, unsigned short* __restrict__ el) {
  int i = blockIdx.x * 256 + threadIdx.x;   // 32768
  int m = i >> 8, y = i & 255;
  int kyi = m & 63;
  int ky = (kyi < 32) ? kyi : (192 + kyi);
  int a = (ky * y) & 255;
  float s, c; sincosf((float)a * (PI_F / 128.f), &s, &c);
  float v = (m < 64) ? c : -s;
  unsigned short h = f2b(v);
  eh[i] = h; el[i] = f2b(v - b2f(h));
}
__global__ void k_tEx(unsigned short* __restrict__ eh, unsigned short* __restrict__ el) {
  int i = blockIdx.x * 256 + threadIdx.x;   // 32768
  int m = i >> 9, k = i & 511;
  int x = k & 255, plane = k >> 8, kx = m & 31;
  int a = (kx * x) & 255;
  float s, c; sincosf((float)a * (PI_F / 128.f), &s, &c);
  float v = (m < 32) ? (plane ? s : c) : (plane ? c : -s);
  unsigned short h = f2b(v);
  eh[i] = h; el[i] = f2b(v - b2f(h));
}
__global__ void k_tWy(unsigned short* __restrict__ eh, unsigned short* __restrict__ el) {
  int i = blockIdx.x * 256 + threadIdx.x;   // 65536
  int row = i >> 7, k = i & 127;
  int y = row & 255, part = row >> 8;
  int kyi = k & 63, plane = k >> 6;
  int ky = (kyi < 32) ? kyi : (192 + kyi);
  int a = (ky * y) & 255;
  float s, c; sincosf((float)a * (PI_F / 128.f), &s, &c);
  float v = (part == 0) ? (plane ? -s : c) : (plane ? c : s);
  unsigned short h = f2b(v);
  eh[i] = h; el[i] = f2b(v - b2f(h));
}
__global__ void k_tCx(unsigned short* __restrict__ eh, unsigned short* __restrict__ el) {
  int i = blockIdx.x * 256 + threadIdx.x;   // 16384
  int x = i >> 6, k = i & 63;
  int kx = k & 31, plane = k >> 5;
  float w = ((kx == 0) ? 1.0f : 2.0f) / 65536.0f;
  int a = (kx * x) & 255;
  float s, c; sincosf((float)a * (PI_F / 128.f), &s, &c);
  float v = plane ? (-w * s) : (w * c);
  unsigned short h = f2b(v);
  eh[i] = h; el[i] = f2b(v - b2f(h));
}

// ---- init: f32 -> bf16 hi/lo split (weights)
__global__ void k_cvt2(const float* __restrict__ src, unsigned short* __restrict__ hi,
                       unsigned short* __restrict__ lo, int n) {
  int i = blockIdx.x * 256 + threadIdx.x;
  if (i < n) {
    float v = src[i];
    unsigned short h = f2b(v);
    hi[i] = h;
    lo[i] = f2b(v - b2f(h));
  }
}

// ---- lift: h packed
__global__ __launch_bounds__(256) void k_lift(const float* __restrict__ x,
                                              const float* __restrict__ pw,
                                              const float* __restrict__ pb,
                                              unsigned* __restrict__ hp) {
  int b = blockIdx.y;
  int yx = blockIdx.x * 256 + threadIdx.x;
  float v = x[(size_t)b * HW + yx];
  size_t o = (size_t)b * NC * HW + yx;
  for (int c = 0; c < NC; ++c)
    hp[o + (size_t)c * HW] = packsplit(v * pw[c] + pb[c]);
}

// ================= spectral GEMM stages (proven bodies, M-split grids) ======
// forward y: Xc[128 rows][(bc,x)] = Ey . h  (M=128, split 2 via blockIdx.y)
__global__ __launch_bounds__(256) void k_fy2(const unsigned* __restrict__ hp,
                                             const unsigned short* __restrict__ Ah,
                                             const unsigned short* __restrict__ Al,
                                             float* __restrict__ Xc, int Ncol) {
  int tid = threadIdx.x, wv = tid >> 6, ln = tid & 63, g16 = ln >> 4, l15 = ln & 15;
  int colbase = blockIdx.x * 128 + wv * 32;
  int rowb = blockIdx.y * 64;
  facc acc[4][2];
#pragma unroll
  for (int mf = 0; mf < 4; ++mf)
#pragma unroll
    for (int pf = 0; pf < 2; ++pf) acc[mf][pf] = (facc)0.f;
#pragma unroll 1
  for (int ks = 0; ks < 8; ++ks) {
    int kof = g16 * 8 + 32 * ks;
    fragu bh[2], bl[2];
#pragma unroll
    for (int pf = 0; pf < 2; ++pf) {
      int col = colbase + pf * 16 + l15;
      size_t o = (size_t)(col >> 8) * HW + (col & 255) + (size_t)kof * 256;
      unsigned u8[8];
#pragma unroll
      for (int j = 0; j < 8; ++j) u8[j] = hp[o + j * 256];
      UNPACK8(u8, bh[pf], bl[pf]);
    }
#pragma unroll
    for (int mf = 0; mf < 4; ++mf) {
      int row = rowb + 16 * mf + l15;
      bfrag ah = *(const bfrag*)(Ah + row * 256 + kof);
      bfrag al = *(const bfrag*)(Al + row * 256 + kof);
#pragma unroll
      for (int pf = 0; pf < 2; ++pf) {
        acc[mf][pf] = MFMA(ah, bh[pf].f, acc[mf][pf]);
        acc[mf][pf] = MFMA(ah, bl[pf].f, acc[mf][pf]);
        acc[mf][pf] = MFMA(al, bh[pf].f, acc[mf][pf]);
      }
    }
  }
#pragma unroll
  for (int mf = 0; mf < 4; ++mf)
#pragma unroll
    for (int pf = 0; pf < 2; ++pf) {
      int col = colbase + pf * 16 + l15;
#pragma unroll
      for (int r = 0; r < 4; ++r)
        Xc[(size_t)(rowb + 16 * mf + 4 * g16 + r) * Ncol + col] = acc[mf][pf][r];
    }
}

// forward x: X2[(bc,kyi)][kx] = Ex . Xc  (M=64, split 2 via blockIdx.y)
__global__ __launch_bounds__(256) void k_fx2(const float* __restrict__ Xc,
                                             const unsigned short* __restrict__ Ah,
                                             const unsigned short* __restrict__ Al,
                                             float* __restrict__ X2r,
                                             float* __restrict__ X2i, int NcXc) {
  int tid = threadIdx.x, wv = tid >> 6, ln = tid & 63, g16 = ln >> 4, l15 = ln & 15;
  int colbase = blockIdx.x * 64 + wv * 16;
  int mb = blockIdx.y * 2;
  facc acc[2];
  acc[0] = (facc)0.f; acc[1] = (facc)0.f;
#pragma unroll 1
  for (int ks = 0; ks < 16; ++ks) {
    int plane = ks >> 3;
    int x0 = (ks & 7) * 32 + g16 * 8;
    int kof = g16 * 8 + 32 * ks;
    bfrag bh, bl;
    {
      int col = colbase + l15;
      const float* p = Xc + (size_t)(plane * 64 + (col & 63)) * NcXc + (col >> 6) * 256 + x0;
      float4 u0 = *(const float4*)p;
      float4 u1 = *(const float4*)(p + 4);
      float tv[8] = {u0.x, u0.y, u0.z, u0.w, u1.x, u1.y, u1.z, u1.w};
#pragma unroll
      for (int j = 0; j < 8; ++j) {
        unsigned short hi = f2b(tv[j]);
        bh[j] = (short)hi;
        bl[j] = (short)f2b(tv[j] - b2f(hi));
      }
    }
#pragma unroll
    for (int mf = 0; mf < 2; ++mf) {
      int row = (mb + mf) * 16 + l15;
      bfrag ah = *(const bfrag*)(Ah + row * 512 + kof);
      bfrag al = *(const bfrag*)(Al + row * 512 + kof);
      acc[mf] = MFMA(ah, bh, acc[mf]);
      acc[mf] = MFMA(ah, bl, acc[mf]);
      acc[mf] = MFMA(al, bh, acc[mf]);
    }
  }
#pragma unroll
  for (int mf = 0; mf < 2; ++mf) {
    int col = colbase + l15;
    int mfg = mb + mf;
    float* base = (mfg >= 2) ? X2i : X2r;
    int kxb = 16 * (mfg & 1) + 4 * g16;
    float4 v = make_float4(acc[mf][0], acc[mf][1], acc[mf][2], acc[mf][3]);
    *(float4*)(base + (size_t)col * 32 + kxb) = v;
  }
}

// ---- spectral channel mix (f32), batch-pair merged: each block handles its
// (kyi,och) for up to 2 batches, reading each weight element ONCE.
__global__ __launch_bounds__(512) void k_spec(const float* __restrict__ X2r,
                                              const float* __restrict__ X2i,
                                              const float* __restrict__ w1r,
                                              const float* __restrict__ w1i,
                                              const float* __restrict__ w2r,
                                              const float* __restrict__ w2i,
                                              float* __restrict__ S, int Ncs, int gc) {
  int och = blockIdx.x & 3;
  int kyi = blockIdx.x >> 2;
  __shared__ float2 xs[2][NC * NM];   // 32 KB
  for (int b = 0; b < gc; ++b)
    for (int idx = threadIdx.x; idx < NC * NM; idx += 512) {
      int i = idx >> 5, kx = idx & 31;
      size_t c2 = ((size_t)(b * 64 + i) * 64 + kyi) * 32 + kx;
      xs[b][idx] = make_float2(X2r[c2], X2i[c2]);
    }
  __syncthreads();
  int kx = threadIdx.x & 31;
  int ol = threadIdx.x >> 5;
  int o = och * 16 + ol;
  int kym = kyi & 31;
  const float* wr = (kyi < 32) ? w1r : w2r;
  const float* wi = (kyi < 32) ? w1i : w2i;
  size_t wb = ((size_t)o * NM + kym) * NM + kx;
  float ar0 = 0.f, ai0 = 0.f, ar1 = 0.f, ai1 = 0.f;
#pragma unroll 4
  for (int i = 0; i < NC; ++i) {
    float wrv = wr[wb + (size_t)i * 65536];
    float wiv = wi[wb + (size_t)i * 65536];
    float2 x0 = xs[0][i * NM + kx];
    ar0 += x0.x * wrv - x0.y * wiv;
    ai0 += x0.x * wiv + x0.y * wrv;
    if (gc > 1) {
      float2 x1 = xs[1][i * NM + kx];
      ar1 += x1.x * wrv - x1.y * wiv;
      ai1 += x1.x * wiv + x1.y * wrv;
    }
  }
  size_t cco0 = (size_t)o * 32 + kx;
  S[(size_t)kyi * Ncs + cco0] = ar0;
  S[(size_t)(64 + kyi) * Ncs + cco0] = ai0;
  if (gc > 1) {
    size_t cco1 = (size_t)(64 + o) * 32 + kx;
    S[(size_t)kyi * Ncs + cco1] = ar1;
    S[(size_t)(64 + kyi) * Ncs + cco1] = ai1;
  }
}

// inverse y: t2[(plane,y)][(bc,kx)] = Wyi . S  (M=512, split 16 via blockIdx.y)
__global__ __launch_bounds__(256) void k_iy2(const float* __restrict__ S,
                                             const unsigned short* __restrict__ Ah,
                                             const unsigned short* __restrict__ Al,
                                             float* __restrict__ t2, int Ncs) {
  int tid = threadIdx.x, wv = tid >> 6, ln = tid & 63, g16 = ln >> 4, l15 = ln & 15;
  int colbase = blockIdx.x * 128 + wv * 32;
  int rowb = blockIdx.y * 32;
  facc acc[2][2];
#pragma unroll
  for (int mf = 0; mf < 2; ++mf)
#pragma unroll
    for (int pf = 0; pf < 2; ++pf) acc[mf][pf] = (facc)0.f;
#pragma unroll 1
  for (int ks = 0; ks < 4; ++ks) {
    int kof = g16 * 8 + 32 * ks;
    bfrag bh[2], bl[2];
#pragma unroll
    for (int pf = 0; pf < 2; ++pf) {
      int col = colbase + pf * 16 + l15;
      const float* p = S + (size_t)kof * Ncs + col;
#pragma unroll
      for (int j = 0; j < 8; ++j) {
        float v = p[(size_t)j * Ncs];
        unsigned short hi = f2b(v);
        bh[pf][j] = (short)hi;
        bl[pf][j] = (short)f2b(v - b2f(hi));
      }
    }
#pragma unroll
    for (int mf = 0; mf < 2; ++mf) {
      int row = rowb + 16 * mf + l15;
      bfrag ah = *(const bfrag*)(Ah + row * 128 + kof);
      bfrag al = *(const bfrag*)(Al + row * 128 + kof);
#pragma unroll
      for (int pf = 0; pf < 2; ++pf) {
        acc[mf][pf] = MFMA(ah, bh[pf], acc[mf][pf]);
        acc[mf][pf] = MFMA(ah, bl[pf], acc[mf][pf]);
        acc[mf][pf] = MFMA(al, bh[pf], acc[mf][pf]);
      }
    }
  }
#pragma unroll
  for (int mf = 0; mf < 2; ++mf)
#pragma unroll
    for (int pf = 0; pf < 2; ++pf) {
      int col = colbase + pf * 16 + l15;
#pragma unroll
      for (int r = 0; r < 4; ++r)
        t2[(size_t)(rowb + 16 * mf + 4 * g16 + r) * Ncs + col] = acc[mf][pf][r];
    }
}

// inverse x (c2r): x1[bc][y][x] = Cx . t2  (M=256, split 4 via blockIdx.y)
__global__ __launch_bounds__(256) void k_ix2(const float* __restrict__ t2,
                                             const unsigned short* __restrict__ Ah,
                                             const unsigned short* __restrict__ Al,
                                             unsigned* __restrict__ x1p, int Nct) {
  int tid = threadIdx.x, wv = tid >> 6, ln = tid & 63, g16 = ln >> 4, l15 = ln & 15;
  int colbase = blockIdx.x * 128 + wv * 32;
  int rowb = blockIdx.y * 64;
  facc acc[4][2];
#pragma unroll
  for (int mf = 0; mf < 4; ++mf)
#pragma unroll
    for (int pf = 0; pf < 2; ++pf) acc[mf][pf] = (facc)0.f;
#pragma unroll 1
  for (int ks = 0; ks < 2; ++ks) {
    int kof = g16 * 8 + 32 * ks;
    bfrag bh[2], bl[2];
#pragma unroll
    for (int pf = 0; pf < 2; ++pf) {
      int col = colbase + pf * 16 + l15;
      const float* p = t2 + (size_t)(ks * 256 + (col & 255)) * Nct + (col >> 8) * 32 + g16 * 8;
      float4 u0 = *(const float4*)p;
      float4 u1 = *(const float4*)(p + 4);
      float tv[8] = {u0.x, u0.y, u0.z, u0.w, u1.x, u1.y, u1.z, u1.w};
#pragma unroll
      for (int j = 0; j < 8; ++j) {
        unsigned short hi = f2b(tv[j]);
        bh[pf][j] = (short)hi;
        bl[pf][j] = (short)f2b(tv[j] - b2f(hi));
      }
    }
#pragma unroll
    for (int mf = 0; mf < 4; ++mf) {
      int row = rowb + 16 * mf + l15;
      bfrag ah = *(const bfrag*)(Ah + row * 64 + kof);
      bfrag al = *(const bfrag*)(Al + row * 64 + kof);
#pragma unroll
      for (int pf = 0; pf < 2; ++pf) {
        acc[mf][pf] = MFMA(ah, bh[pf], acc[mf][pf]);
        acc[mf][pf] = MFMA(ah, bl[pf], acc[mf][pf]);
        acc[mf][pf] = MFMA(al, bh[pf], acc[mf][pf]);
      }
    }
  }
#pragma unroll
  for (int mf = 0; mf < 4; ++mf)
#pragma unroll
    for (int pf = 0; pf < 2; ++pf) {
      int col = colbase + pf * 16 + l15;
      int bc = col >> 8, y = col & 255;
      int xb = rowb + 16 * mf + 4 * g16;
      uint4 pv;
      pv.x = packsplit(acc[mf][pf][0]);
      pv.y = packsplit(acc[mf][pf][1]);
      pv.z = packsplit(acc[mf][pf][2]);
      pv.w = packsplit(acc[mf][pf][3]);
      size_t o = (size_t)bc * HW + y * 256 + xb;
      *(uint4*)(x1p + o) = pv;
    }
}

// ---- fused channel MLP + skip, LDS-staged packed tiles + v_perm unpack.
__global__ __launch_bounds__(256) void k_fmlp(const unsigned* __restrict__ x1p,
                                              unsigned* __restrict__ Hp,
                                              const unsigned short* __restrict__ w1h,
                                              const unsigned short* __restrict__ w1l,
                                              const float* __restrict__ b1p,
                                              const unsigned short* __restrict__ w2h,
                                              const unsigned short* __restrict__ w2l,
                                              const unsigned short* __restrict__ skh,
                                              const unsigned short* __restrict__ skl,
                                              const float* __restrict__ b2p,
                                              const float* __restrict__ skbp,
                                              int do_gelu) {
  __shared__ unsigned xt[64 * 64];   // x1 tile, later mid (packed)   16 KB
  __shared__ unsigned ht[64 * 64];   // h tile, later out (packed)    16 KB
  int tid = threadIdx.x, wv = tid >> 6, ln = tid & 63, g16 = ln >> 4, l15 = ln & 15;
  int b = blockIdx.y;
  int px0 = blockIdx.x * 64;
  const unsigned* xq = x1p + (size_t)b * NC * HW;
  unsigned* hq = Hp + (size_t)b * NC * HW;

  for (int i = tid; i < 1024; i += 256) {
    int ch = i >> 4, q = (i & 15) * 4;
    int la = swz(ch, q);
    *(uint4*)(xt + la) = *(const uint4*)(xq + (size_t)ch * HW + px0 + q);
    *(uint4*)(ht + la) = *(const uint4*)(hq + (size_t)ch * HW + px0 + q);
  }
  __syncthreads();

  int rw = 16 * wv;

  // ---- GEMM1
  facc a1[4];
#pragma unroll
  for (int pf = 0; pf < 4; ++pf) {
    facc z;
#pragma unroll
    for (int r = 0; r < 4; ++r) z[r] = b1p[rw + 4 * g16 + r];
    a1[pf] = z;
  }
#pragma unroll
  for (int ks = 0; ks < 2; ++ks) {
    bfrag ah = *(const bfrag*)(w1h + (rw + l15) * 64 + g16 * 8 + 32 * ks);
    bfrag al = *(const bfrag*)(w1l + (rw + l15) * 64 + g16 * 8 + 32 * ks);
#pragma unroll
    for (int pf = 0; pf < 4; ++pf) {
      unsigned u8[8];
#pragma unroll
      for (int j = 0; j < 8; ++j)
        u8[j] = xt[swz(g16 * 8 + j + 32 * ks, pf * 16 + l15)];
      fragu bh, bl;
      UNPACK8(u8, bh, bl);
      a1[pf] = MFMA(ah, bh.f, a1[pf]);
      a1[pf] = MFMA(ah, bl.f, a1[pf]);
      a1[pf] = MFMA(al, bh.f, a1[pf]);
    }
  }
  __syncthreads();

#pragma unroll
  for (int pf = 0; pf < 4; ++pf)
#pragma unroll
    for (int r = 0; r < 4; ++r)
      xt[swz(rw + 4 * g16 + r, pf * 16 + l15)] = packsplit(gelu_f(a1[pf][r]));
  __syncthreads();

  // ---- GEMM2 + skip
  facc a2[4];
#pragma unroll
  for (int pf = 0; pf < 4; ++pf) {
    facc z;
#pragma unroll
    for (int r = 0; r < 4; ++r) {
      int o = rw + 4 * g16 + r;
      z[r] = b2p[o] + skbp[o];
    }
    a2[pf] = z;
  }
#pragma unroll
  for (int ks = 0; ks < 2; ++ks) {
    bfrag w2hf = *(const bfrag*)(w2h + (rw + l15) * 64 + g16 * 8 + 32 * ks);
    bfrag w2lf = *(const bfrag*)(w2l + (rw + l15) * 64 + g16 * 8 + 32 * ks);
    bfrag skhf = *(const bfrag*)(skh + (rw + l15) * 64 + g16 * 8 + 32 * ks);
    bfrag sklf = *(const bfrag*)(skl + (rw + l15) * 64 + g16 * 8 + 32 * ks);
#pragma unroll
    for (int pf = 0; pf < 4; ++pf) {
      unsigned um[8], uh[8];
#pragma unroll
      for (int j = 0; j < 8; ++j) {
        int la = swz(g16 * 8 + j + 32 * ks, pf * 16 + l15);
        um[j] = xt[la];
        uh[j] = ht[la];
      }
      fragu mh, mlo, hh, hlo;
      UNPACK8(um, mh, mlo);
      UNPACK8(uh, hh, hlo);
      a2[pf] = MFMA(w2hf, mh.f, a2[pf]);
      a2[pf] = MFMA(w2hf, mlo.f, a2[pf]);
      a2[pf] = MFMA(w2lf, mh.f, a2[pf]);
      a2[pf] = MFMA(skhf, hh.f, a2[pf]);
      a2[pf] = MFMA(skhf, hlo.f, a2[pf]);
      a2[pf] = MFMA(sklf, hh.f, a2[pf]);
    }
  }
  __syncthreads();

#pragma unroll
  for (int pf = 0; pf < 4; ++pf)
#pragma unroll
    for (int r = 0; r < 4; ++r) {
      float v = a2[pf][r];
      if (do_gelu) v = gelu_f(v);
      ht[swz(rw + 4 * g16 + r, pf * 16 + l15)] = packsplit(v);
    }
  __syncthreads();

  for (int i = tid; i < 1024; i += 256) {
    int ch = i >> 4, q = (i & 15) * 4;
    *(uint4*)(hq + (size_t)ch * HW + px0 + q) = *(const uint4*)(ht + swz(ch, q));
  }
}

// ---- projection, single launch: loops both 128-row halves internally.
__global__ __launch_bounds__(256) void k_pproj(const unsigned* __restrict__ hp,
                                               const unsigned short* __restrict__ q1h,
                                               const unsigned short* __restrict__ q1l,
                                               const float* __restrict__ q1bp,
                                               const float* __restrict__ q2wp,
                                               const float* __restrict__ q2bp,
                                               float* __restrict__ out) {
  __shared__ unsigned short q1sh[128 * 72];   // 18.4 KB
  __shared__ unsigned short q1sl[128 * 72];
  __shared__ float q1bs[128], q2s[128];
  int tid = threadIdx.x;
  int wv = tid >> 6, ln = tid & 63, g16 = ln >> 4, l15 = ln & 15;
  float q2bias = q2bp[0];
  int colbase = blockIdx.x * 128 + wv * 32;
  float part[2] = {0.f, 0.f};

#pragma unroll 1
  for (int R0 = 0; R0 < 256; R0 += 128) {
    __syncthreads();   // prev half's LDS reads complete before restage
    for (int i = tid; i < 2048; i += 256) {
      int row = i >> 4, c4 = (i & 15) * 4;
      ushort4 vh = *(const ushort4*)(q1h + (size_t)(R0 + row) * 64 + c4);
      ushort4 vl = *(const ushort4*)(q1l + (size_t)(R0 + row) * 64 + c4);
      *(ushort4*)(q1sh + row * 72 + c4) = vh;
      *(ushort4*)(q1sl + row * 72 + c4) = vl;
    }
    if (tid < 128) {
      q1bs[tid] = q1bp[R0 + tid];
      q2s[tid] = q2wp[R0 + tid];
    }
    __syncthreads();

    facc acc[8][2];
#pragma unroll
    for (int mf = 0; mf < 8; ++mf)
#pragma unroll
      for (int pf = 0; pf < 2; ++pf) {
        facc z;
#pragma unroll
        for (int r = 0; r < 4; ++r) z[r] = q1bs[16 * mf + 4 * g16 + r];
        acc[mf][pf] = z;
      }
#pragma unroll
    for (int ks = 0; ks < 2; ++ks) {
      fragu bh[2], bl[2];
#pragma unroll
      for (int pf = 0; pf < 2; ++pf) {
        int col = colbase + pf * 16 + l15;
        size_t o = (size_t)(col >> 16) * NC * HW + (col & 65535);
        unsigned u8[8];
#pragma unroll
        for (int j = 0; j < 8; ++j)
          u8[j] = hp[o + (size_t)(g16 * 8 + j + 32 * ks) * HW];
        UNPACK8(u8, bh[pf], bl[pf]);
      }
#pragma unroll
      for (int mf = 0; mf < 8; ++mf) {
        bfrag ah = *(const bfrag*)(q1sh + (16 * mf + l15) * 72 + g16 * 8 + 32 * ks);
        bfrag al = *(const bfrag*)(q1sl + (16 * mf + l15) * 72 + g16 * 8 + 32 * ks);
#pragma unroll
        for (int pf = 0; pf < 2; ++pf) {
          acc[mf][pf] = MFMA(ah, bh[pf].f, acc[mf][pf]);
          acc[mf][pf] = MFMA(ah, bl[pf].f, acc[mf][pf]);
          acc[mf][pf] = MFMA(al, bh[pf].f, acc[mf][pf]);
        }
      }
    }
#pragma unroll
    for (int pf = 0; pf < 2; ++pf)
#pragma unroll
      for (int mf = 0; mf < 8; ++mf)
#pragma unroll
        for (int r = 0; r < 4; ++r)
          part[pf] += gelu_f(acc[mf][pf][r]) * q2s[16 * mf + 4 * g16 + r];
  }

#pragma unroll
  for (int pf = 0; pf < 2; ++pf) {
    float partial = part[pf];
    partial += __shfl_xor(partial, 16);
    partial += __shfl_xor(partial, 32);
    if (ln < 16)
      out[colbase + pf * 16 + ln] = partial + q2bias;
  }
}

extern "C" void kernel_launch(void* const* d_in, const int* in_sizes, int n_in,
                              void* d_out, int out_size, void* d_ws, size_t ws_size,
                              hipStream_t stream) {
  const float* x    = (const float*)d_in[0];
  const float* p_w  = (const float*)d_in[1];
  const float* p_b  = (const float*)d_in[2];
  const float* sw1r = (const float*)d_in[3];
  const float* sw1i = (const float*)d_in[4];
  const float* sw2r = (const float*)d_in[5];
  const float* sw2i = (const float*)d_in[6];
  const float* m1w  = (const float*)d_in[7];
  const float* m1b  = (const float*)d_in[8];
  const float* m2w  = (const float*)d_in[9];
  const float* m2b  = (const float*)d_in[10];
  const float* skw  = (const float*)d_in[11];
  const float* skb  = (const float*)d_in[12];
  const float* q1w  = (const float*)d_in[13];
  const float* q1b  = (const float*)d_in[14];
  const float* q2w  = (const float*)d_in[15];
  const float* q2b  = (const float*)d_in[16];

  const size_t MB = 1048576ULL;
  const size_t TBL = 1 * MB;
  int g = 16;
  while (g > 1 && (size_t)g * 36 * MB + TBL > ws_size) g >>= 1;
  if ((size_t)g * 36 * MB + TBL > ws_size) return;

  char* wsb = (char*)d_ws;
  unsigned short* Eyh = (unsigned short*)(wsb + 0);        // 64 KB
  unsigned short* Eyl = (unsigned short*)(wsb + 65536);
  unsigned short* Exh = (unsigned short*)(wsb + 131072);   // 64 KB
  unsigned short* Exl = (unsigned short*)(wsb + 196608);
  unsigned short* Wyh = (unsigned short*)(wsb + 262144);   // 128 KB
  unsigned short* Wyl = (unsigned short*)(wsb + 393216);
  unsigned short* Cxh = (unsigned short*)(wsb + 524288);   // 32 KB
  unsigned short* Cxl = (unsigned short*)(wsb + 557056);
  unsigned short* m1h = (unsigned short*)(wsb + 589824);   // 32 KB each
  unsigned short* m1l = (unsigned short*)(wsb + 622592);
  unsigned short* m2h = (unsigned short*)(wsb + 655360);
  unsigned short* m2l = (unsigned short*)(wsb + 688128);
  unsigned short* skh = (unsigned short*)(wsb + 720896);
  unsigned short* skl = (unsigned short*)(wsb + 753664);
  unsigned short* q1h = (unsigned short*)(wsb + 786432);
  unsigned short* q1l = (unsigned short*)(wsb + 819200);

  char* base = wsb + TBL;
  unsigned* Hp  = (unsigned*)base;                                    // g*16 MB
  unsigned* x1p = (unsigned*)(base + (size_t)g * 16 * MB);            // g*16 MB
  float* Xc  = (float*)x1p;                                           // alias g*8 MB
  float* X2r = (float*)(base + (size_t)g * 24 * MB);                  // alias g*0.5 MB
  float* X2i = (float*)(base + (size_t)g * 24 * MB + (size_t)g * 524288ULL);
  float* S   = (float*)(base + (size_t)g * 25 * MB);                  // alias g*1 MB
  float* t2  = (float*)(base + (size_t)g * 32 * MB);                  // g*4 MB

  k_tEy<<<128, 256, 0, stream>>>(Eyh, Eyl);
  k_tEx<<<128, 256, 0, stream>>>(Exh, Exl);
  k_tWy<<<256, 256, 0, stream>>>(Wyh, Wyl);
  k_tCx<<<64, 256, 0, stream>>>(Cxh, Cxl);
  k_cvt2<<<64, 256, 0, stream>>>(m1w, m1h, m1l, 16384);
  k_cvt2<<<64, 256, 0, stream>>>(m2w, m2h, m2l, 16384);
  k_cvt2<<<64, 256, 0, stream>>>(skw, skh, skl, 16384);
  k_cvt2<<<64, 256, 0, stream>>>(q1w, q1h, q1l, 16384);

  int Nfy = g * 16384;   // (bc,x) cols
  int Ncs = g * 2048;    // (bc,kx) cols

  for (int b0 = 0; b0 < 16; b0 += g) {
    k_lift<<<dim3(256, g), 256, 0, stream>>>(x + (size_t)b0 * HW, p_w, p_b, Hp);
    for (int l = 0; l < 4; ++l) {
      k_fy2<<<dim3(g * 128, 2), 256, 0, stream>>>(Hp, Eyh, Eyl, Xc, Nfy);
      k_fx2<<<dim3(g * 64, 2), 256, 0, stream>>>(Xc, Exh, Exl, X2r, X2i, Nfy);
      // batch-pair-merged spectral mix: ceil(g/2) launches, weights read once/pair
      for (int bp = 0; bp < g; bp += 2) {
        int gc = (g - bp >= 2) ? 2 : 1;
        k_spec<<<dim3(256), 512, 0, stream>>>(X2r + (size_t)bp * 131072,
                                              X2i + (size_t)bp * 131072,
                                              sw1r + (size_t)l * 4194304,
                                              sw1i + (size_t)l * 4194304,
                                              sw2r + (size_t)l * 4194304,
                                              sw2i + (size_t)l * 4194304,
                                              S + (size_t)bp * 2048, Ncs, gc);
      }
      k_iy2<<<dim3(g * 16, 16), 256, 0, stream>>>(S, Wyh, Wyl, t2, Ncs);
      k_ix2<<<dim3(g * 128, 4), 256, 0, stream>>>(t2, Cxh, Cxl, x1p, Ncs);
      k_fmlp<<<dim3(1024, g), 256, 0, stream>>>(x1p, Hp,
                                                m1h + l * 4096, m1l + l * 4096, m1b + l * 64,
                                                m2h + l * 4096, m2l + l * 4096,
                                                skh + l * 4096, skl + l * 4096,
                                                m2b + l * 64, skb + l * 64, (l < 3) ? 1 : 0);
    }
    float* outc = (float*)d_out + (size_t)b0 * HW;
    k_pproj<<<g * 512, 256, 0, stream>>>(Hp, q1h, q1l, q1b, q2w, q2b, outc);
  }
}

// Round 21
// 3402.336 us; speedup vs baseline: 1.2073x; 1.2073x over previous
//
#include <hip/hip_runtime.h>
#include <math.h>

#define NC 64
#define NH 256
#define NW 256
#define NM 32
#define NKY 64
#define HW 65536

typedef short bfrag __attribute__((ext_vector_type(8)));   // 8 bf16 (4 VGPR)
typedef float facc  __attribute__((ext_vector_type(4)));   // 4 f32 acc
#define MFMA(a,b,c) __builtin_amdgcn_mfma_f32_16x16x32_bf16(a,b,c,0,0,0)

static constexpr float PI_F = 3.14159265358979323846f;

__device__ __forceinline__ unsigned short f2b(float f) {  // f32 -> bf16 RNE
  unsigned b = __float_as_uint(f);
  return (unsigned short)((b + 0x7FFFu + ((b >> 16) & 1u)) >> 16);
}
__device__ __forceinline__ float b2f(unsigned short h) {
  return __uint_as_float((unsigned)h << 16);
}
// pack hi/lo split of f32 into one uint: (lo<<16)|hi
__device__ __forceinline__ unsigned packsplit(float v) {
  unsigned short hi = f2b(v);
  unsigned short lo = f2b(v - b2f(hi));
  return (unsigned)hi | ((unsigned)lo << 16);
}
// LDS tile addressing: [ch][64 px], XOR-swizzled to spread quarter-wave rows
__device__ __forceinline__ int swz(int ch, int px) {
  return ch * 64 + (px ^ (((ch >> 3) & 3) << 4));
}
// build hi/lo bfrags from 8 packed uints via v_perm (2 ops per uint pair)
#define UNPACK8(U, BH, BL)                                              \
  {                                                                     \
    BH.q.x = __builtin_amdgcn_perm(U[1], U[0], 0x05040100u);            \
    BH.q.y = __builtin_amdgcn_perm(U[3], U[2], 0x05040100u);            \
    BH.q.z = __builtin_amdgcn_perm(U[5], U[4], 0x05040100u);            \
    BH.q.w = __builtin_amdgcn_perm(U[7], U[6], 0x05040100u);            \
    BL.q.x = __builtin_amdgcn_perm(U[1], U[0], 0x07060302u);            \
    BL.q.y = __builtin_amdgcn_perm(U[3], U[2], 0x07060302u);            \
    BL.q.z = __builtin_amdgcn_perm(U[5], U[4], 0x07060302u);            \
    BL.q.w = __builtin_amdgcn_perm(U[7], U[6], 0x07060302u);            \
  }
typedef union { bfrag f; uint4 q; } fragu;

// branchless erf-based exact GELU (A&S 7.1.26, |err| < 1.5e-7)
__device__ __forceinline__ float gelu_f(float x) {
  float z = fabsf(x) * 0.70710678118654752f;
  float t = 1.0f / (1.0f + 0.3275911f * z);
  float e = __expf(-z * z);
  float p = t * (0.254829592f + t * (-0.284496736f + t * (1.421413741f +
            t * (-1.453152027f + t * 1.061405429f))));
  float er = copysignf(1.0f - p * e, x);
  return 0.5f * x * (1.0f + er);
}

// ================= table builders (split-bf16 DFT matrices) =================
__global__ void k_tEy(unsigned short* __restrict__ eh, unsigned short* __restrict__ el) {
  int i = blockIdx.x * 256 + threadIdx.x;   // 32768
  int m = i >> 8, y = i & 255;
  int kyi = m & 63;
  int ky = (kyi < 32) ? kyi : (192 + kyi);
  int a = (ky * y) & 255;
  float s, c; sincosf((float)a * (PI_F / 128.f), &s, &c);
  float v = (m < 64) ? c : -s;
  unsigned short h = f2b(v);
  eh[i] = h; el[i] = f2b(v - b2f(h));
}
__global__ void k_tEx(unsigned short* __restrict__ eh, unsigned short* __restrict__ el) {
  int i = blockIdx.x * 256 + threadIdx.x;   // 32768
  int m = i >> 9, k = i & 511;
  int x = k & 255, plane = k >> 8, kx = m & 31;
  int a = (kx * x) & 255;
  float s, c; sincosf((float)a * (PI_F / 128.f), &s, &c);
  float v = (m < 32) ? (plane ? s : c) : (plane ? c : -s);
  unsigned short h = f2b(v);
  eh[i] = h; el[i] = f2b(v - b2f(h));
}
__global__ void k_tWy(unsigned short* __restrict__ eh, unsigned short* __restrict__ el) {
  int i = blockIdx.x * 256 + threadIdx.x;   // 65536
  int row = i >> 7, k = i & 127;
  int y = row & 255, part = row >> 8;
  int kyi = k & 63, plane = k >> 6;
  int ky = (kyi < 32) ? kyi : (192 + kyi);
  int a = (ky * y) & 255;
  float s, c; sincosf((float)a * (PI_F / 128.f), &s, &c);
  float v = (part == 0) ? (plane ? -s : c) : (plane ? c : s);
  unsigned short h = f2b(v);
  eh[i] = h; el[i] = f2b(v - b2f(h));
}
__global__ void k_tCx(unsigned short* __restrict__ eh, unsigned short* __restrict__ el) {
  int i = blockIdx.x * 256 + threadIdx.x;   // 16384
  int x = i >> 6, k = i & 63;
  int kx = k & 31, plane = k >> 5;
  float w = ((kx == 0) ? 1.0f : 2.0f) / 65536.0f;
  int a = (kx * x) & 255;
  float s, c; sincosf((float)a * (PI_F / 128.f), &s, &c);
  float v = plane ? (-w * s) : (w * c);
  unsigned short h = f2b(v);
  eh[i] = h; el[i] = f2b(v - b2f(h));
}

// ---- init: f32 -> bf16 hi/lo split (weights)
__global__ void k_cvt2(const float* __restrict__ src, unsigned short* __restrict__ hi,
                       unsigned short* __restrict__ lo, int n) {
  int i = blockIdx.x * 256 + threadIdx.x;
  if (i < n) {
    float v = src[i];
    unsigned short h = f2b(v);
    hi[i] = h;
    lo[i] = f2b(v - b2f(h));
  }
}

// ---- lift: h packed
__global__ __launch_bounds__(256) void k_lift(const float* __restrict__ x,
                                              const float* __restrict__ pw,
                                              const float* __restrict__ pb,
                                              unsigned* __restrict__ hp) {
  int b = blockIdx.y;
  int yx = blockIdx.x * 256 + threadIdx.x;
  float v = x[(size_t)b * HW + yx];
  size_t o = (size_t)b * NC * HW + yx;
  for (int c = 0; c < NC; ++c)
    hp[o + (size_t)c * HW] = packsplit(v * pw[c] + pb[c]);
}

// ================= spectral GEMM stages (proven bodies, M-split grids) ======
// forward y: Xc[128 rows][(bc,x)] = Ey . h  (M=128, split 2 via blockIdx.y)
__global__ __launch_bounds__(256) void k_fy2(const unsigned* __restrict__ hp,
                                             const unsigned short* __restrict__ Ah,
                                             const unsigned short* __restrict__ Al,
                                             float* __restrict__ Xc, int Ncol) {
  int tid = threadIdx.x, wv = tid >> 6, ln = tid & 63, g16 = ln >> 4, l15 = ln & 15;
  int colbase = blockIdx.x * 128 + wv * 32;
  int rowb = blockIdx.y * 64;
  facc acc[4][2];
#pragma unroll
  for (int mf = 0; mf < 4; ++mf)
#pragma unroll
    for (int pf = 0; pf < 2; ++pf) acc[mf][pf] = (facc)0.f;
#pragma unroll 1
  for (int ks = 0; ks < 8; ++ks) {
    int kof = g16 * 8 + 32 * ks;
    fragu bh[2], bl[2];
#pragma unroll
    for (int pf = 0; pf < 2; ++pf) {
      int col = colbase + pf * 16 + l15;
      size_t o = (size_t)(col >> 8) * HW + (col & 255) + (size_t)kof * 256;
      unsigned u8[8];
#pragma unroll
      for (int j = 0; j < 8; ++j) u8[j] = hp[o + j * 256];
      UNPACK8(u8, bh[pf], bl[pf]);
    }
#pragma unroll
    for (int mf = 0; mf < 4; ++mf) {
      int row = rowb + 16 * mf + l15;
      bfrag ah = *(const bfrag*)(Ah + row * 256 + kof);
      bfrag al = *(const bfrag*)(Al + row * 256 + kof);
#pragma unroll
      for (int pf = 0; pf < 2; ++pf) {
        acc[mf][pf] = MFMA(ah, bh[pf].f, acc[mf][pf]);
        acc[mf][pf] = MFMA(ah, bl[pf].f, acc[mf][pf]);
        acc[mf][pf] = MFMA(al, bh[pf].f, acc[mf][pf]);
      }
    }
  }
#pragma unroll
  for (int mf = 0; mf < 4; ++mf)
#pragma unroll
    for (int pf = 0; pf < 2; ++pf) {
      int col = colbase + pf * 16 + l15;
#pragma unroll
      for (int r = 0; r < 4; ++r)
        Xc[(size_t)(rowb + 16 * mf + 4 * g16 + r) * Ncol + col] = acc[mf][pf][r];
    }
}

// forward x: X2[(bc,kyi)][kx] = Ex . Xc  (M=64, split 2 via blockIdx.y)
__global__ __launch_bounds__(256) void k_fx2(const float* __restrict__ Xc,
                                             const unsigned short* __restrict__ Ah,
                                             const unsigned short* __restrict__ Al,
                                             float* __restrict__ X2r,
                                             float* __restrict__ X2i, int NcXc) {
  int tid = threadIdx.x, wv = tid >> 6, ln = tid & 63, g16 = ln >> 4, l15 = ln & 15;
  int colbase = blockIdx.x * 64 + wv * 16;
  int mb = blockIdx.y * 2;
  facc acc[2];
  acc[0] = (facc)0.f; acc[1] = (facc)0.f;
#pragma unroll 1
  for (int ks = 0; ks < 16; ++ks) {
    int plane = ks >> 3;
    int x0 = (ks & 7) * 32 + g16 * 8;
    int kof = g16 * 8 + 32 * ks;
    bfrag bh, bl;
    {
      int col = colbase + l15;
      const float* p = Xc + (size_t)(plane * 64 + (col & 63)) * NcXc + (col >> 6) * 256 + x0;
      float4 u0 = *(const float4*)p;
      float4 u1 = *(const float4*)(p + 4);
      float tv[8] = {u0.x, u0.y, u0.z, u0.w, u1.x, u1.y, u1.z, u1.w};
#pragma unroll
      for (int j = 0; j < 8; ++j) {
        unsigned short hi = f2b(tv[j]);
        bh[j] = (short)hi;
        bl[j] = (short)f2b(tv[j] - b2f(hi));
      }
    }
#pragma unroll
    for (int mf = 0; mf < 2; ++mf) {
      int row = (mb + mf) * 16 + l15;
      bfrag ah = *(const bfrag*)(Ah + row * 512 + kof);
      bfrag al = *(const bfrag*)(Al + row * 512 + kof);
      acc[mf] = MFMA(ah, bh, acc[mf]);
      acc[mf] = MFMA(ah, bl, acc[mf]);
      acc[mf] = MFMA(al, bh, acc[mf]);
    }
  }
#pragma unroll
  for (int mf = 0; mf < 2; ++mf) {
    int col = colbase + l15;
    int mfg = mb + mf;
    float* base = (mfg >= 2) ? X2i : X2r;
    int kxb = 16 * (mfg & 1) + 4 * g16;
    float4 v = make_float4(acc[mf][0], acc[mf][1], acc[mf][2], acc[mf][3]);
    *(float4*)(base + (size_t)col * 32 + kxb) = v;
  }
}

// ---- spectral channel mix (f32): S[(plane,kyi)][(bc,kx)] = X2 . W
__global__ __launch_bounds__(512) void k_spec(const float* __restrict__ X2r,
                                              const float* __restrict__ X2i,
                                              const float* __restrict__ w1r,
                                              const float* __restrict__ w1i,
                                              const float* __restrict__ w2r,
                                              const float* __restrict__ w2i,
                                              float* __restrict__ S, int Ncs) {
  int b = blockIdx.y;
  int och = blockIdx.x & 3;
  int kyi = blockIdx.x >> 2;
  __shared__ float2 xs[NC * NM];
  for (int idx = threadIdx.x; idx < NC * NM; idx += 512) {
    int i = idx >> 5, kx = idx & 31;
    size_t c2 = ((size_t)(b * 64 + i) * 64 + kyi) * 32 + kx;
    xs[idx] = make_float2(X2r[c2], X2i[c2]);
  }
  __syncthreads();
  int kx = threadIdx.x & 31;
  int ol = threadIdx.x >> 5;
  int o = och * 16 + ol;
  int kym = kyi & 31;
  const float* wr = (kyi < 32) ? w1r : w2r;
  const float* wi = (kyi < 32) ? w1i : w2i;
  size_t wb = ((size_t)o * NM + kym) * NM + kx;
  float ar = 0.f, ai = 0.f;
#pragma unroll 4
  for (int i = 0; i < NC; ++i) {
    float2 xv = xs[i * NM + kx];
    float wrv = wr[wb + (size_t)i * 65536];
    float wiv = wi[wb + (size_t)i * 65536];
    ar += xv.x * wrv - xv.y * wiv;
    ai += xv.x * wiv + xv.y * wrv;
  }
  size_t cco = (size_t)(b * 64 + o) * 32 + kx;
  S[(size_t)kyi * Ncs + cco] = ar;
  S[(size_t)(64 + kyi) * Ncs + cco] = ai;
}

// inverse y: t2[(plane,y)][(bc,kx)] = Wyi . S  (M=512, split 16 via blockIdx.y)
__global__ __launch_bounds__(256) void k_iy2(const float* __restrict__ S,
                                             const unsigned short* __restrict__ Ah,
                                             const unsigned short* __restrict__ Al,
                                             float* __restrict__ t2, int Ncs) {
  int tid = threadIdx.x, wv = tid >> 6, ln = tid & 63, g16 = ln >> 4, l15 = ln & 15;
  int colbase = blockIdx.x * 128 + wv * 32;
  int rowb = blockIdx.y * 32;
  facc acc[2][2];
#pragma unroll
  for (int mf = 0; mf < 2; ++mf)
#pragma unroll
    for (int pf = 0; pf < 2; ++pf) acc[mf][pf] = (facc)0.f;
#pragma unroll 1
  for (int ks = 0; ks < 4; ++ks) {
    int kof = g16 * 8 + 32 * ks;
    bfrag bh[2], bl[2];
#pragma unroll
    for (int pf = 0; pf < 2; ++pf) {
      int col = colbase + pf * 16 + l15;
      const float* p = S + (size_t)kof * Ncs + col;
#pragma unroll
      for (int j = 0; j < 8; ++j) {
        float v = p[(size_t)j * Ncs];
        unsigned short hi = f2b(v);
        bh[pf][j] = (short)hi;
        bl[pf][j] = (short)f2b(v - b2f(hi));
      }
    }
#pragma unroll
    for (int mf = 0; mf < 2; ++mf) {
      int row = rowb + 16 * mf + l15;
      bfrag ah = *(const bfrag*)(Ah + row * 128 + kof);
      bfrag al = *(const bfrag*)(Al + row * 128 + kof);
#pragma unroll
      for (int pf = 0; pf < 2; ++pf) {
        acc[mf][pf] = MFMA(ah, bh[pf], acc[mf][pf]);
        acc[mf][pf] = MFMA(ah, bl[pf], acc[mf][pf]);
        acc[mf][pf] = MFMA(al, bh[pf], acc[mf][pf]);
      }
    }
  }
#pragma unroll
  for (int mf = 0; mf < 2; ++mf)
#pragma unroll
    for (int pf = 0; pf < 2; ++pf) {
      int col = colbase + pf * 16 + l15;
#pragma unroll
      for (int r = 0; r < 4; ++r)
        t2[(size_t)(rowb + 16 * mf + 4 * g16 + r) * Ncs + col] = acc[mf][pf][r];
    }
}

// inverse x (c2r): x1[bc][y][x] = Cx . t2  (M=256, split 4 via blockIdx.y)
__global__ __launch_bounds__(256) void k_ix2(const float* __restrict__ t2,
                                             const unsigned short* __restrict__ Ah,
                                             const unsigned short* __restrict__ Al,
                                             unsigned* __restrict__ x1p, int Nct) {
  int tid = threadIdx.x, wv = tid >> 6, ln = tid & 63, g16 = ln >> 4, l15 = ln & 15;
  int colbase = blockIdx.x * 128 + wv * 32;
  int rowb = blockIdx.y * 64;
  facc acc[4][2];
#pragma unroll
  for (int mf = 0; mf < 4; ++mf)
#pragma unroll
    for (int pf = 0; pf < 2; ++pf) acc[mf][pf] = (facc)0.f;
#pragma unroll 1
  for (int ks = 0; ks < 2; ++ks) {
    int kof = g16 * 8 + 32 * ks;
    bfrag bh[2], bl[2];
#pragma unroll
    for (int pf = 0; pf < 2; ++pf) {
      int col = colbase + pf * 16 + l15;
      const float* p = t2 + (size_t)(ks * 256 + (col & 255)) * Nct + (col >> 8) * 32 + g16 * 8;
      float4 u0 = *(const float4*)p;
      float4 u1 = *(const float4*)(p + 4);
      float tv[8] = {u0.x, u0.y, u0.z, u0.w, u1.x, u1.y, u1.z, u1.w};
#pragma unroll
      for (int j = 0; j < 8; ++j) {
        unsigned short hi = f2b(tv[j]);
        bh[pf][j] = (short)hi;
        bl[pf][j] = (short)f2b(tv[j] - b2f(hi));
      }
    }
#pragma unroll
    for (int mf = 0; mf < 4; ++mf) {
      int row = rowb + 16 * mf + l15;
      bfrag ah = *(const bfrag*)(Ah + row * 64 + kof);
      bfrag al = *(const bfrag*)(Al + row * 64 + kof);
#pragma unroll
      for (int pf = 0; pf < 2; ++pf) {
        acc[mf][pf] = MFMA(ah, bh[pf], acc[mf][pf]);
        acc[mf][pf] = MFMA(ah, bl[pf], acc[mf][pf]);
        acc[mf][pf] = MFMA(al, bh[pf], acc[mf][pf]);
      }
    }
  }
#pragma unroll
  for (int mf = 0; mf < 4; ++mf)
#pragma unroll
    for (int pf = 0; pf < 2; ++pf) {
      int col = colbase + pf * 16 + l15;
      int bc = col >> 8, y = col & 255;
      int xb = rowb + 16 * mf + 4 * g16;
      uint4 pv;
      pv.x = packsplit(acc[mf][pf][0]);
      pv.y = packsplit(acc[mf][pf][1]);
      pv.z = packsplit(acc[mf][pf][2]);
      pv.w = packsplit(acc[mf][pf][3]);
      size_t o = (size_t)bc * HW + y * 256 + xb;
      *(uint4*)(x1p + o) = pv;
    }
}

// ---- fused channel MLP + skip, LDS-staged packed tiles + v_perm unpack.
__global__ __launch_bounds__(256) void k_fmlp(const unsigned* __restrict__ x1p,
                                              unsigned* __restrict__ Hp,
                                              const unsigned short* __restrict__ w1h,
                                              const unsigned short* __restrict__ w1l,
                                              const float* __restrict__ b1p,
                                              const unsigned short* __restrict__ w2h,
                                              const unsigned short* __restrict__ w2l,
                                              const unsigned short* __restrict__ skh,
                                              const unsigned short* __restrict__ skl,
                                              const float* __restrict__ b2p,
                                              const float* __restrict__ skbp,
                                              int do_gelu) {
  __shared__ unsigned xt[64 * 64];   // x1 tile, later mid (packed)   16 KB
  __shared__ unsigned ht[64 * 64];   // h tile, later out (packed)    16 KB
  int tid = threadIdx.x, wv = tid >> 6, ln = tid & 63, g16 = ln >> 4, l15 = ln & 15;
  int b = blockIdx.y;
  int px0 = blockIdx.x * 64;
  const unsigned* xq = x1p + (size_t)b * NC * HW;
  unsigned* hq = Hp + (size_t)b * NC * HW;

  for (int i = tid; i < 1024; i += 256) {
    int ch = i >> 4, q = (i & 15) * 4;
    int la = swz(ch, q);
    *(uint4*)(xt + la) = *(const uint4*)(xq + (size_t)ch * HW + px0 + q);
    *(uint4*)(ht + la) = *(const uint4*)(hq + (size_t)ch * HW + px0 + q);
  }
  __syncthreads();

  int rw = 16 * wv;

  // ---- GEMM1
  facc a1[4];
#pragma unroll
  for (int pf = 0; pf < 4; ++pf) {
    facc z;
#pragma unroll
    for (int r = 0; r < 4; ++r) z[r] = b1p[rw + 4 * g16 + r];
    a1[pf] = z;
  }
#pragma unroll
  for (int ks = 0; ks < 2; ++ks) {
    bfrag ah = *(const bfrag*)(w1h + (rw + l15) * 64 + g16 * 8 + 32 * ks);
    bfrag al = *(const bfrag*)(w1l + (rw + l15) * 64 + g16 * 8 + 32 * ks);
#pragma unroll
    for (int pf = 0; pf < 4; ++pf) {
      unsigned u8[8];
#pragma unroll
      for (int j = 0; j < 8; ++j)
        u8[j] = xt[swz(g16 * 8 + j + 32 * ks, pf * 16 + l15)];
      fragu bh, bl;
      UNPACK8(u8, bh, bl);
      a1[pf] = MFMA(ah, bh.f, a1[pf]);
      a1[pf] = MFMA(ah, bl.f, a1[pf]);
      a1[pf] = MFMA(al, bh.f, a1[pf]);
    }
  }
  __syncthreads();

#pragma unroll
  for (int pf = 0; pf < 4; ++pf)
#pragma unroll
    for (int r = 0; r < 4; ++r)
      xt[swz(rw + 4 * g16 + r, pf * 16 + l15)] = packsplit(gelu_f(a1[pf][r]));
  __syncthreads();

  // ---- GEMM2 + skip
  facc a2[4];
#pragma unroll
  for (int pf = 0; pf < 4; ++pf) {
    facc z;
#pragma unroll
    for (int r = 0; r < 4; ++r) {
      int o = rw + 4 * g16 + r;
      z[r] = b2p[o] + skbp[o];
    }
    a2[pf] = z;
  }
#pragma unroll
  for (int ks = 0; ks < 2; ++ks) {
    bfrag w2hf = *(const bfrag*)(w2h + (rw + l15) * 64 + g16 * 8 + 32 * ks);
    bfrag w2lf = *(const bfrag*)(w2l + (rw + l15) * 64 + g16 * 8 + 32 * ks);
    bfrag skhf = *(const bfrag*)(skh + (rw + l15) * 64 + g16 * 8 + 32 * ks);
    bfrag sklf = *(const bfrag*)(skl + (rw + l15) * 64 + g16 * 8 + 32 * ks);
#pragma unroll
    for (int pf = 0; pf < 4; ++pf) {
      unsigned um[8], uh[8];
#pragma unroll
      for (int j = 0; j < 8; ++j) {
        int la = swz(g16 * 8 + j + 32 * ks, pf * 16 + l15);
        um[j] = xt[la];
        uh[j] = ht[la];
      }
      fragu mh, mlo, hh, hlo;
      UNPACK8(um, mh, mlo);
      UNPACK8(uh, hh, hlo);
      a2[pf] = MFMA(w2hf, mh.f, a2[pf]);
      a2[pf] = MFMA(w2hf, mlo.f, a2[pf]);
      a2[pf] = MFMA(w2lf, mh.f, a2[pf]);
      a2[pf] = MFMA(skhf, hh.f, a2[pf]);
      a2[pf] = MFMA(skhf, hlo.f, a2[pf]);
      a2[pf] = MFMA(sklf, hh.f, a2[pf]);
    }
  }
  __syncthreads();

#pragma unroll
  for (int pf = 0; pf < 4; ++pf)
#pragma unroll
    for (int r = 0; r < 4; ++r) {
      float v = a2[pf][r];
      if (do_gelu) v = gelu_f(v);
      ht[swz(rw + 4 * g16 + r, pf * 16 + l15)] = packsplit(v);
    }
  __syncthreads();

  for (int i = tid; i < 1024; i += 256) {
    int ch = i >> 4, q = (i & 15) * 4;
    *(uint4*)(hq + (size_t)ch * HW + px0 + q) = *(const uint4*)(ht + swz(ch, q));
  }
}

// ---- projection, single launch: loops both 128-row halves internally.
__global__ __launch_bounds__(256) void k_pproj(const unsigned* __restrict__ hp,
                                               const unsigned short* __restrict__ q1h,
                                               const unsigned short* __restrict__ q1l,
                                               const float* __restrict__ q1bp,
                                               const float* __restrict__ q2wp,
                                               const float* __restrict__ q2bp,
                                               float* __restrict__ out) {
  __shared__ unsigned short q1sh[128 * 72];   // 18.4 KB
  __shared__ unsigned short q1sl[128 * 72];
  __shared__ float q1bs[128], q2s[128];
  int tid = threadIdx.x;
  int wv = tid >> 6, ln = tid & 63, g16 = ln >> 4, l15 = ln & 15;
  float q2bias = q2bp[0];
  int colbase = blockIdx.x * 128 + wv * 32;
  float part[2] = {0.f, 0.f};

#pragma unroll 1
  for (int R0 = 0; R0 < 256; R0 += 128) {
    __syncthreads();   // prev half's LDS reads complete before restage
    for (int i = tid; i < 2048; i += 256) {
      int row = i >> 4, c4 = (i & 15) * 4;
      ushort4 vh = *(const ushort4*)(q1h + (size_t)(R0 + row) * 64 + c4);
      ushort4 vl = *(const ushort4*)(q1l + (size_t)(R0 + row) * 64 + c4);
      *(ushort4*)(q1sh + row * 72 + c4) = vh;
      *(ushort4*)(q1sl + row * 72 + c4) = vl;
    }
    if (tid < 128) {
      q1bs[tid] = q1bp[R0 + tid];
      q2s[tid] = q2wp[R0 + tid];
    }
    __syncthreads();

    facc acc[8][2];
#pragma unroll
    for (int mf = 0; mf < 8; ++mf)
#pragma unroll
      for (int pf = 0; pf < 2; ++pf) {
        facc z;
#pragma unroll
        for (int r = 0; r < 4; ++r) z[r] = q1bs[16 * mf + 4 * g16 + r];
        acc[mf][pf] = z;
      }
#pragma unroll
    for (int ks = 0; ks < 2; ++ks) {
      fragu bh[2], bl[2];
#pragma unroll
      for (int pf = 0; pf < 2; ++pf) {
        int col = colbase + pf * 16 + l15;
        size_t o = (size_t)(col >> 16) * NC * HW + (col & 65535);
        unsigned u8[8];
#pragma unroll
        for (int j = 0; j < 8; ++j)
          u8[j] = hp[o + (size_t)(g16 * 8 + j + 32 * ks) * HW];
        UNPACK8(u8, bh[pf], bl[pf]);
      }
#pragma unroll
      for (int mf = 0; mf < 8; ++mf) {
        bfrag ah = *(const bfrag*)(q1sh + (16 * mf + l15) * 72 + g16 * 8 + 32 * ks);
        bfrag al = *(const bfrag*)(q1sl + (16 * mf + l15) * 72 + g16 * 8 + 32 * ks);
#pragma unroll
        for (int pf = 0; pf < 2; ++pf) {
          acc[mf][pf] = MFMA(ah, bh[pf].f, acc[mf][pf]);
          acc[mf][pf] = MFMA(ah, bl[pf].f, acc[mf][pf]);
          acc[mf][pf] = MFMA(al, bh[pf].f, acc[mf][pf]);
        }
      }
    }
#pragma unroll
    for (int pf = 0; pf < 2; ++pf)
#pragma unroll
      for (int mf = 0; mf < 8; ++mf)
#pragma unroll
        for (int r = 0; r < 4; ++r)
          part[pf] += gelu_f(acc[mf][pf][r]) * q2s[16 * mf + 4 * g16 + r];
  }

#pragma unroll
  for (int pf = 0; pf < 2; ++pf) {
    float partial = part[pf];
    partial += __shfl_xor(partial, 16);
    partial += __shfl_xor(partial, 32);
    if (ln < 16)
      out[colbase + pf * 16 + ln] = partial + q2bias;
  }
}

extern "C" void kernel_launch(void* const* d_in, const int* in_sizes, int n_in,
                              void* d_out, int out_size, void* d_ws, size_t ws_size,
                              hipStream_t stream) {
  const float* x    = (const float*)d_in[0];
  const float* p_w  = (const float*)d_in[1];
  const float* p_b  = (const float*)d_in[2];
  const float* sw1r = (const float*)d_in[3];
  const float* sw1i = (const float*)d_in[4];
  const float* sw2r = (const float*)d_in[5];
  const float* sw2i = (const float*)d_in[6];
  const float* m1w  = (const float*)d_in[7];
  const float* m1b  = (const float*)d_in[8];
  const float* m2w  = (const float*)d_in[9];
  const float* m2b  = (const float*)d_in[10];
  const float* skw  = (const float*)d_in[11];
  const float* skb  = (const float*)d_in[12];
  const float* q1w  = (const float*)d_in[13];
  const float* q1b  = (const float*)d_in[14];
  const float* q2w  = (const float*)d_in[15];
  const float* q2b  = (const float*)d_in[16];

  const size_t MB = 1048576ULL;
  const size_t TBL = 1 * MB;
  int g = 16;
  while (g > 1 && (size_t)g * 36 * MB + TBL > ws_size) g >>= 1;
  if ((size_t)g * 36 * MB + TBL > ws_size) return;

  char* wsb = (char*)d_ws;
  unsigned short* Eyh = (unsigned short*)(wsb + 0);        // 64 KB
  unsigned short* Eyl = (unsigned short*)(wsb + 65536);
  unsigned short* Exh = (unsigned short*)(wsb + 131072);   // 64 KB
  unsigned short* Exl = (unsigned short*)(wsb + 196608);
  unsigned short* Wyh = (unsigned short*)(wsb + 262144);   // 128 KB
  unsigned short* Wyl = (unsigned short*)(wsb + 393216);
  unsigned short* Cxh = (unsigned short*)(wsb + 524288);   // 32 KB
  unsigned short* Cxl = (unsigned short*)(wsb + 557056);
  unsigned short* m1h = (unsigned short*)(wsb + 589824);   // 32 KB each
  unsigned short* m1l = (unsigned short*)(wsb + 622592);
  unsigned short* m2h = (unsigned short*)(wsb + 655360);
  unsigned short* m2l = (unsigned short*)(wsb + 688128);
  unsigned short* skh = (unsigned short*)(wsb + 720896);
  unsigned short* skl = (unsigned short*)(wsb + 753664);
  unsigned short* q1h = (unsigned short*)(wsb + 786432);
  unsigned short* q1l = (unsigned short*)(wsb + 819200);

  char* base = wsb + TBL;
  unsigned* Hp  = (unsigned*)base;                                    // g*16 MB
  unsigned* x1p = (unsigned*)(base + (size_t)g * 16 * MB);            // g*16 MB
  float* Xc  = (float*)x1p;                                           // alias g*8 MB
  float* X2r = (float*)(base + (size_t)g * 24 * MB);                  // alias g*0.5 MB
  float* X2i = (float*)(base + (size_t)g * 24 * MB + (size_t)g * 524288ULL);
  float* S   = (float*)(base + (size_t)g * 25 * MB);                  // alias g*1 MB
  float* t2  = (float*)(base + (size_t)g * 32 * MB);                  // g*4 MB

  k_tEy<<<128, 256, 0, stream>>>(Eyh, Eyl);
  k_tEx<<<128, 256, 0, stream>>>(Exh, Exl);
  k_tWy<<<256, 256, 0, stream>>>(Wyh, Wyl);
  k_tCx<<<64, 256, 0, stream>>>(Cxh, Cxl);
  k_cvt2<<<64, 256, 0, stream>>>(m1w, m1h, m1l, 16384);
  k_cvt2<<<64, 256, 0, stream>>>(m2w, m2h, m2l, 16384);
  k_cvt2<<<64, 256, 0, stream>>>(skw, skh, skl, 16384);
  k_cvt2<<<64, 256, 0, stream>>>(q1w, q1h, q1l, 16384);

  int Nfy = g * 16384;   // (bc,x) cols
  int Ncs = g * 2048;    // (bc,kx) cols

  for (int b0 = 0; b0 < 16; b0 += g) {
    k_lift<<<dim3(256, g), 256, 0, stream>>>(x + (size_t)b0 * HW, p_w, p_b, Hp);
    for (int l = 0; l < 4; ++l) {
      k_fy2<<<dim3(g * 128, 2), 256, 0, stream>>>(Hp, Eyh, Eyl, Xc, Nfy);
      k_fx2<<<dim3(g * 64, 2), 256, 0, stream>>>(Xc, Exh, Exl, X2r, X2i, Nfy);
      k_spec<<<dim3(256, g), 512, 0, stream>>>(X2r, X2i,
                                               sw1r + (size_t)l * 4194304,
                                               sw1i + (size_t)l * 4194304,
                                               sw2r + (size_t)l * 4194304,
                                               sw2i + (size_t)l * 4194304, S, Ncs);
      k_iy2<<<dim3(g * 16, 16), 256, 0, stream>>>(S, Wyh, Wyl, t2, Ncs);
      k_ix2<<<dim3(g * 128, 4), 256, 0, stream>>>(t2, Cxh, Cxl, x1p, Ncs);
      k_fmlp<<<dim3(1024, g), 256, 0, stream>>>(x1p, Hp,
                                                m1h + l * 4096, m1l + l * 4096, m1b + l * 64,
                                                m2h + l * 4096, m2l + l * 4096,
                                                skh + l * 4096, skl + l * 4096,
                                                m2b + l * 64, skb + l * 64, (l < 3) ? 1 : 0);
    }
    float* outc = (float*)d_out + (size_t)b0 * HW;
    k_pproj<<<g * 512, 256, 0, stream>>>(Hp, q1h, q1l, q1b, q2w, q2b, outc);
  }
}